// Round 12
// baseline (110.577 us; speedup 1.0000x reference)
//
#include <hip/hip_runtime.h>
#include <hip/hip_bf16.h>
#include <math.h>

#define B_ 32
#define T_ 128
#define C_ 64
#define E_ 8
#define HID_ 32

#define LOG2E 1.44269504088896341f

__device__ __forceinline__ float fast_rcp(float x) { return __builtin_amdgcn_rcpf(x); }
__device__ __forceinline__ float fast_sigmoid(float x) {
    return fast_rcp(1.0f + exp2f(-LOG2E * x));
}
__device__ __forceinline__ float fast_tanh(float x) {
    float xc = fminf(fmaxf(x, -15.0f), 15.0f);
    float t = exp2f(2.0f * LOG2E * xc);
    return (t - 1.0f) * fast_rcp(t + 1.0f);
}

// ---------------------------------------------------------------------------
// K1: GRU with inline xp. 8 chains per 64-thread block (all lanes hot).
// grid = 256, block = 64. Fast sigmoid/tanh (rcp-based) shorten the serial
// dependence chain (no IEEE div refinement on the critical path).
// ---------------------------------------------------------------------------
__global__ __launch_bounds__(64) void k_gru(
    const float* __restrict__ x, const float* __restrict__ W_in, const float* __restrict__ b_in,
    const float* __restrict__ W_ih, const float* __restrict__ W_hh,
    const float* __restrict__ b_ih, const float* __restrict__ b_hh,
    float* __restrict__ hs, float* __restrict__ fh)
{
    const int tid = threadIdx.x;
    const int ci = tid >> 3;                       // chain-in-block 0..7
    const int e = tid & 7;
    const int chain = blockIdx.x * 8 + ci;         // b*C + c
    const int b = chain >> 6;
    const int c = chain & 63;

    __shared__ float wsh[8][C_];
    __shared__ float xc[8][T_ + 1];

#pragma unroll
    for (int i = 0; i < 8; ++i) {
        int idx = tid * 8 + i;
        int ci2 = idx >> 6;
        int cc = (blockIdx.x * 8 + ci2) & 63;
        wsh[ci2][idx & 63] = W_in[cc * C_ + (idx & 63)];
    }
    __syncthreads();

    const float bi = b_in[c];
    for (int tt = 0; tt < 16; ++tt) {
        const int t = e * 16 + tt;
        const float4* xr = (const float4*)(x + (b * T_ + t) * C_);
        float a = bi;
#pragma unroll
        for (int k4 = 0; k4 < 16; ++k4) {
            float4 xv = xr[k4];
            a = fmaf(xv.x, wsh[ci][k4 * 4 + 0], a);
            a = fmaf(xv.y, wsh[ci][k4 * 4 + 1], a);
            a = fmaf(xv.z, wsh[ci][k4 * 4 + 2], a);
            a = fmaf(xv.w, wsh[ci][k4 * 4 + 3], a);
        }
        xc[ci][t] = a;
    }
    __syncthreads();

    float wr[E_], wz[E_], wn[E_];
#pragma unroll
    for (int j = 0; j < E_; ++j) {
        wr[j] = W_hh[(c * 24 + 0 * E_ + e) * E_ + j];
        wz[j] = W_hh[(c * 24 + 1 * E_ + e) * E_ + j];
        wn[j] = W_hh[(c * 24 + 2 * E_ + e) * E_ + j];
    }
    const float wir = W_ih[c * 24 + e], wiz = W_ih[c * 24 + E_ + e], win = W_ih[c * 24 + 2 * E_ + e];
    const float bir = b_ih[c * 24 + e], biz = b_ih[c * 24 + E_ + e], bin_ = b_ih[c * 24 + 2 * E_ + e];
    const float bhr = b_hh[c * 24 + e], bhz = b_hh[c * 24 + E_ + e], bhn = b_hh[c * 24 + 2 * E_ + e];

    float h = 0.0f;
    float* ho = hs + (size_t)chain * T_ * E_ + e;
    for (int t = 0; t < T_; ++t) {
        float xv = xc[ci][t];
        float gr = fmaf(xv, wir, bir) + bhr;
        float gz = fmaf(xv, wiz, biz) + bhz;
        float gn = fmaf(xv, win, bin_);
        float hn = bhn;
#pragma unroll
        for (int j = 0; j < E_; ++j) {
            float hj = __shfl(h, j, E_);
            gr = fmaf(hj, wr[j], gr);
            gz = fmaf(hj, wz[j], gz);
            hn = fmaf(hj, wn[j], hn);
        }
        float r = fast_sigmoid(gr);
        float z = fast_sigmoid(gz);
        float nn = fast_tanh(fmaf(r, hn, gn));
        h = fmaf(z, h - nn, nn);               // (1-z)*nn + z*h
        ho[t * E_] = h;
    }
    fh[chain * E_ + e] = h;
}

// ---------------------------------------------------------------------------
// K2: attention, 2-row tiling + lane s-split. grid = B*C, block = 128.
// thread: r = tid>>1 (rows r and r+64), p = tid&1 (s in [64p, 64p+64)).
// Partial l/acc combined with the lane^1 partner via shfl_xor.
// ---------------------------------------------------------------------------
__global__ __launch_bounds__(128) void k_attn(
    const float* __restrict__ hs, const float* __restrict__ W_qkv, const float* __restrict__ b_qkv,
    const float* __restrict__ W_o, const float* __restrict__ b_o,
    float* __restrict__ feat_imp, float* __restrict__ tsf_imp)
{
    const int bc = blockIdx.x;
    const int b = bc >> 6, c = bc & 63;
    const int tid = threadIdx.x;
    const int r = tid >> 1;
    const int p = tid & 1;

    __shared__ __align__(16) float hsl[T_][E_];
    __shared__ __align__(16) float ks[T_][E_];
    __shared__ __align__(16) float vs[T_][E_];
    __shared__ float wssum[E_];
    __shared__ float bsum_s;
    __shared__ float red[T_];

    // stage hidden rows (coalesced 32B/thread)
    {
        const float4* hp = (const float4*)(hs + (size_t)bc * T_ * E_ + tid * E_);
        ((float4*)&hsl[tid][0])[0] = hp[0];
        ((float4*)&hsl[tid][0])[1] = hp[1];
    }
    if (tid < E_) {
        float ws = 0.0f;
#pragma unroll
        for (int fp = 0; fp < E_; ++fp) ws += W_o[fp * E_ + tid];
        wssum[tid] = ws;
    }
    if (tid == E_) {
        float bs = 0.0f;
#pragma unroll
        for (int fp = 0; fp < E_; ++fp) bs += b_o[fp];
        bsum_s = bs;
    }
    __syncthreads();

    // k,v for s=tid; q (pre-scaled for exp2) for rows r and r+64
    const float qscale = 0.70710678118654752f * LOG2E;
    {
        float hr[E_];
#pragma unroll
        for (int j = 0; j < E_; ++j) hr[j] = hsl[tid][j];
#pragma unroll
        for (int f = 0; f < E_; ++f) {
            float a = b_qkv[E_ + f];
#pragma unroll
            for (int j = 0; j < E_; ++j) a = fmaf(hr[j], W_qkv[(E_ + f) * E_ + j], a);
            ks[tid][f] = a;
        }
#pragma unroll
        for (int f = 0; f < E_; ++f) {
            float a = b_qkv[2 * E_ + f];
#pragma unroll
            for (int j = 0; j < E_; ++j) a = fmaf(hr[j], W_qkv[(2 * E_ + f) * E_ + j], a);
            vs[tid][f] = a;
        }
    }
    float q0[E_], q1[E_];
#pragma unroll
    for (int f = 0; f < E_; ++f) {
        float a0 = b_qkv[f], a1 = b_qkv[f];
#pragma unroll
        for (int j = 0; j < E_; ++j) {
            float w = W_qkv[f * E_ + j];
            a0 = fmaf(hsl[r][j], w, a0);
            a1 = fmaf(hsl[r + 64][j], w, a1);
        }
        q0[f] = a0 * qscale;
        q1[f] = a1 * qscale;
    }
    __syncthreads();

    // s-loop over this thread's half, both rows share each k/v read
    float l0[4] = {0.f,0.f,0.f,0.f}, l1[4] = {0.f,0.f,0.f,0.f};
    float a0[E_] = {0.f,0.f,0.f,0.f,0.f,0.f,0.f,0.f};
    float a1[E_] = {0.f,0.f,0.f,0.f,0.f,0.f,0.f,0.f};
    const float* kb = &ks[p * 64][0];
    const float* vb = &vs[p * 64][0];
#pragma unroll 8
    for (int i = 0; i < 64; ++i) {
        float4 k0 = *(const float4*)(kb + i * 8);
        float4 k1 = *(const float4*)(kb + i * 8 + 4);
        float4 v0 = *(const float4*)(vb + i * 8);
        float4 v1 = *(const float4*)(vb + i * 8 + 4);
        float p00 = exp2f(fmaf(q0[1], k0.y, q0[0] * k0.x));
        float p01 = exp2f(fmaf(q0[3], k0.w, q0[2] * k0.z));
        float p02 = exp2f(fmaf(q0[5], k1.y, q0[4] * k1.x));
        float p03 = exp2f(fmaf(q0[7], k1.w, q0[6] * k1.z));
        float p10 = exp2f(fmaf(q1[1], k0.y, q1[0] * k0.x));
        float p11 = exp2f(fmaf(q1[3], k0.w, q1[2] * k0.z));
        float p12 = exp2f(fmaf(q1[5], k1.y, q1[4] * k1.x));
        float p13 = exp2f(fmaf(q1[7], k1.w, q1[6] * k1.z));
        l0[0] += p00; l0[1] += p01; l0[2] += p02; l0[3] += p03;
        l1[0] += p10; l1[1] += p11; l1[2] += p12; l1[3] += p13;
        a0[0] = fmaf(p00, v0.x, a0[0]); a0[1] = fmaf(p00, v0.y, a0[1]);
        a0[2] = fmaf(p01, v0.z, a0[2]); a0[3] = fmaf(p01, v0.w, a0[3]);
        a0[4] = fmaf(p02, v1.x, a0[4]); a0[5] = fmaf(p02, v1.y, a0[5]);
        a0[6] = fmaf(p03, v1.z, a0[6]); a0[7] = fmaf(p03, v1.w, a0[7]);
        a1[0] = fmaf(p10, v0.x, a1[0]); a1[1] = fmaf(p10, v0.y, a1[1]);
        a1[2] = fmaf(p11, v0.z, a1[2]); a1[3] = fmaf(p11, v0.w, a1[3]);
        a1[4] = fmaf(p12, v1.x, a1[4]); a1[5] = fmaf(p12, v1.y, a1[5]);
        a1[6] = fmaf(p13, v1.z, a1[6]); a1[7] = fmaf(p13, v1.w, a1[7]);
    }

    // combine with lane^1 partner (same rows, other s-half)
#pragma unroll
    for (int i = 0; i < 4; ++i) {
        l0[i] += __shfl_xor(l0[i], 1);
        l1[i] += __shfl_xor(l1[i], 1);
    }
#pragma unroll
    for (int j = 0; j < E_; ++j) {
        a0[j] += __shfl_xor(a0[j], 1);
        a1[j] += __shfl_xor(a1[j], 1);
    }

    // p=0 finalizes row r; p=1 finalizes row r+64
    const float* lm = p ? l1 : l0;
    const float* am = p ? a1 : a0;
    const int row = p ? (r + 64) : r;
    float S = bsum_s;
#pragma unroll
    for (int f = 0; f < E_; ++f)
        S = fmaf(am[f] * fast_rcp(lm[f >> 1]), wssum[f], S);

    tsf_imp[(size_t)b * T_ * C_ + (size_t)row * C_ + c] = fast_sigmoid(S);
    red[row] = S;
    __syncthreads();
    for (int off = 64; off > 0; off >>= 1) {
        if (tid < off) red[tid] += red[tid + off];
        __syncthreads();
    }
    if (tid == 0) feat_imp[bc] = fast_sigmoid(red[0]);
}

// ---------------------------------------------------------------------------
// K3: ts_imp. grid = B*T, block = 64.
// ---------------------------------------------------------------------------
__global__ __launch_bounds__(64) void k_ts(
    const float* __restrict__ x,
    const float* __restrict__ W_ts1, const float* __restrict__ b_ts1,
    const float* __restrict__ W_ts2, const float* __restrict__ b_ts2,
    float* __restrict__ ts_imp)
{
    const int bt = blockIdx.x;
    const int tid = threadIdx.x;
    __shared__ float xs[C_];
    __shared__ float h1[16];
    xs[tid] = x[bt * C_ + tid];
    __syncthreads();
    if (tid < 16) {
        float a = b_ts1[tid];
#pragma unroll
        for (int k = 0; k < C_; ++k) a = fmaf(xs[k], W_ts1[tid * C_ + k], a);
        h1[tid] = 0.5f * a * (1.0f + erff(a * 0.70710678118654752f));
    }
    __syncthreads();
    if (tid == 0) {
        float s = b_ts2[0];
#pragma unroll
        for (int k = 0; k < 16; ++k) s = fmaf(h1[k], W_ts2[k], s);
        ts_imp[bt] = fast_sigmoid(s);
    }
}

// ---------------------------------------------------------------------------
// K4: out0[b,o] = b_out[o] + sum_k fh[b*C..][k] * W_out[o,k]. grid = B.
// ---------------------------------------------------------------------------
__global__ __launch_bounds__(64) void k_out(
    const float* __restrict__ fh, const float* __restrict__ W_out, const float* __restrict__ b_out,
    float* __restrict__ out0)
{
    const int b = blockIdx.x;
    const int tid = threadIdx.x;
    __shared__ float hf[C_ * E_];
    const float4* src = (const float4*)(fh + (b * C_ + tid) * E_);
    float4* dst = (float4*)(hf + tid * E_);
    dst[0] = src[0];
    dst[1] = src[1];
    __syncthreads();
    if (tid < HID_) {
        float a = b_out[tid];
        const float* wo = W_out + tid * (C_ * E_);
        for (int k = 0; k < C_ * E_; ++k) a = fmaf(hf[k], wo[k], a);
        out0[b * HID_ + tid] = a;
    }
}

// ---------------------------------------------------------------------------
extern "C" void kernel_launch(void* const* d_in, const int* in_sizes, int n_in,
                              void* d_out, int out_size, void* d_ws, size_t ws_size,
                              hipStream_t stream) {
    (void)in_sizes; (void)n_in; (void)out_size; (void)ws_size;

    float* out0 = (float*)d_out;                 // (B, HID)    1024
    float* feat = out0 + B_ * HID_;              // (B, C)      2048
    float* tsim = feat + B_ * C_;                // (B, T)      4096
    float* tsf  = tsim + B_ * T_;                // (B, T, C) 262144

    const float* x     = (const float*)d_in[0];
    const float* W_in  = (const float*)d_in[1];
    const float* b_in  = (const float*)d_in[2];
    const float* W_ts1 = (const float*)d_in[3];
    const float* b_ts1 = (const float*)d_in[4];
    const float* W_ts2 = (const float*)d_in[5];
    const float* b_ts2 = (const float*)d_in[6];
    const float* W_ih  = (const float*)d_in[7];
    const float* W_hh  = (const float*)d_in[8];
    const float* b_ih  = (const float*)d_in[9];
    const float* b_hh  = (const float*)d_in[10];
    const float* W_qkv = (const float*)d_in[11];
    const float* b_qkv = (const float*)d_in[12];
    const float* W_o   = (const float*)d_in[13];
    const float* b_o   = (const float*)d_in[14];
    const float* W_out = (const float*)d_in[15];
    const float* b_out = (const float*)d_in[16];

    float* fhb = (float*)d_ws;                   // fh 16K
    float* hsb = fhb + B_ * C_ * E_;             // hs 8M

    hipLaunchKernelGGL(k_gru, dim3(B_ * C_ / 8), dim3(64), 0, stream,
                       x, W_in, b_in, W_ih, W_hh, b_ih, b_hh, hsb, fhb);
    hipLaunchKernelGGL(k_attn, dim3(B_ * C_), dim3(128), 0, stream,
                       hsb, W_qkv, b_qkv, W_o, b_o, feat, tsf);
    hipLaunchKernelGGL(k_ts, dim3(B_ * T_), dim3(64), 0, stream,
                       x, W_ts1, b_ts1, W_ts2, b_ts2, tsim);
    hipLaunchKernelGGL(k_out, dim3(B_), dim3(64), 0, stream,
                       fhb, W_out, b_out, out0);
}

// Round 13
// 94.270 us; speedup vs baseline: 1.1730x; 1.1730x over previous
//
#include <hip/hip_runtime.h>
#include <hip/hip_bf16.h>
#include <math.h>

#define B_ 32
#define T_ 128
#define C_ 64
#define E_ 8
#define HID_ 32

#define LOG2E 1.44269504088896341f

__device__ __forceinline__ float fast_rcp(float x) { return __builtin_amdgcn_rcpf(x); }
__device__ __forceinline__ float fast_sigmoid(float x) {
    return fast_rcp(1.0f + exp2f(-LOG2E * x));
}
__device__ __forceinline__ float fast_tanh(float x) {
    float xc = fminf(fmaxf(x, -15.0f), 15.0f);
    float t = exp2f(2.0f * LOG2E * xc);
    return (t - 1.0f) * fast_rcp(t + 1.0f);
}

// ---------------------------------------------------------------------------
// K1: GRU with inline xp. 8 chains per 64-thread block (all lanes hot).
// grid = 256, block = 64. (unchanged from round 12)
// ---------------------------------------------------------------------------
__global__ __launch_bounds__(64) void k_gru(
    const float* __restrict__ x, const float* __restrict__ W_in, const float* __restrict__ b_in,
    const float* __restrict__ W_ih, const float* __restrict__ W_hh,
    const float* __restrict__ b_ih, const float* __restrict__ b_hh,
    float* __restrict__ hs, float* __restrict__ fh)
{
    const int tid = threadIdx.x;
    const int ci = tid >> 3;
    const int e = tid & 7;
    const int chain = blockIdx.x * 8 + ci;
    const int b = chain >> 6;
    const int c = chain & 63;

    __shared__ float wsh[8][C_];
    __shared__ float xc[8][T_ + 1];

#pragma unroll
    for (int i = 0; i < 8; ++i) {
        int idx = tid * 8 + i;
        int ci2 = idx >> 6;
        int cc = (blockIdx.x * 8 + ci2) & 63;
        wsh[ci2][idx & 63] = W_in[cc * C_ + (idx & 63)];
    }
    __syncthreads();

    const float bi = b_in[c];
    for (int tt = 0; tt < 16; ++tt) {
        const int t = e * 16 + tt;
        const float4* xr = (const float4*)(x + (b * T_ + t) * C_);
        float a = bi;
#pragma unroll
        for (int k4 = 0; k4 < 16; ++k4) {
            float4 xv = xr[k4];
            a = fmaf(xv.x, wsh[ci][k4 * 4 + 0], a);
            a = fmaf(xv.y, wsh[ci][k4 * 4 + 1], a);
            a = fmaf(xv.z, wsh[ci][k4 * 4 + 2], a);
            a = fmaf(xv.w, wsh[ci][k4 * 4 + 3], a);
        }
        xc[ci][t] = a;
    }
    __syncthreads();

    float wr[E_], wz[E_], wn[E_];
#pragma unroll
    for (int j = 0; j < E_; ++j) {
        wr[j] = W_hh[(c * 24 + 0 * E_ + e) * E_ + j];
        wz[j] = W_hh[(c * 24 + 1 * E_ + e) * E_ + j];
        wn[j] = W_hh[(c * 24 + 2 * E_ + e) * E_ + j];
    }
    const float wir = W_ih[c * 24 + e], wiz = W_ih[c * 24 + E_ + e], win = W_ih[c * 24 + 2 * E_ + e];
    const float bir = b_ih[c * 24 + e], biz = b_ih[c * 24 + E_ + e], bin_ = b_ih[c * 24 + 2 * E_ + e];
    const float bhr = b_hh[c * 24 + e], bhz = b_hh[c * 24 + E_ + e], bhn = b_hh[c * 24 + 2 * E_ + e];

    float h = 0.0f;
    float* ho = hs + (size_t)chain * T_ * E_ + e;
    for (int t = 0; t < T_; ++t) {
        float xv = xc[ci][t];
        float gr = fmaf(xv, wir, bir) + bhr;
        float gz = fmaf(xv, wiz, biz) + bhz;
        float gn = fmaf(xv, win, bin_);
        float hn = bhn;
#pragma unroll
        for (int j = 0; j < E_; ++j) {
            float hj = __shfl(h, j, E_);
            gr = fmaf(hj, wr[j], gr);
            gz = fmaf(hj, wz[j], gz);
            hn = fmaf(hj, wn[j], hn);
        }
        float r = fast_sigmoid(gr);
        float z = fast_sigmoid(gz);
        float nn = fast_tanh(fmaf(r, hn, gn));
        h = fmaf(z, h - nn, nn);
        ho[t * E_] = h;
    }
    fh[chain * E_ + e] = h;
}

// ---------------------------------------------------------------------------
// K2: attention with W_o folded through PV. grid = B*C, block = 256.
// thread (t = tid&127, p = tid>>7); p covers s in [p*64, p*64+64).
// u[s][h] = sum_{d in head h} v[s,d]*wssum[d] -> S_h = sum_s p_h(t,s)*u[s][h].
// ---------------------------------------------------------------------------
__global__ __launch_bounds__(256) void k_attn(
    const float* __restrict__ hs, const float* __restrict__ W_qkv, const float* __restrict__ b_qkv,
    const float* __restrict__ W_o, const float* __restrict__ b_o,
    float* __restrict__ feat_imp, float* __restrict__ tsf_imp)
{
    const int bc = blockIdx.x;
    const int b = bc >> 6, c = bc & 63;
    const int tid = threadIdx.x;
    const int t = tid & 127;
    const int p = tid >> 7;

    __shared__ __align__(16) float ks[T_][E_];
    __shared__ __align__(16) float us[T_][4];
    __shared__ __align__(16) float pacc[T_][8];    // p=1 partials: l[4], S4[4]
    __shared__ float wssum[E_];
    __shared__ float bsum_s;
    __shared__ float red[T_];

    // W_o column sums + bias sum (tiny)
    if (tid < E_) {
        float ws = 0.0f;
#pragma unroll
        for (int fp = 0; fp < E_; ++fp) ws += W_o[fp * E_ + tid];
        wssum[tid] = ws;
    }
    if (tid == E_) {
        float bs = 0.0f;
#pragma unroll
        for (int fp = 0; fp < E_; ++fp) bs += b_o[fp];
        bsum_s = bs;
    }
    __syncthreads();

    // hidden row (both halves load same row; coalesced, L2-hot)
    float hrow[E_];
    {
        const float4* hp = (const float4*)(hs + (size_t)bc * T_ * E_ + t * E_);
        float4 h0 = hp[0], h1 = hp[1];
        hrow[0] = h0.x; hrow[1] = h0.y; hrow[2] = h0.z; hrow[3] = h0.w;
        hrow[4] = h1.x; hrow[5] = h1.y; hrow[6] = h1.z; hrow[7] = h1.w;
    }

    // q (pre-scaled for exp2); k staged by p=0; v->u staged by p=1
    const float qscale = 0.70710678118654752f * LOG2E;
    float q[E_];
#pragma unroll
    for (int f = 0; f < E_; ++f) {
        float a = b_qkv[f];
#pragma unroll
        for (int j = 0; j < E_; ++j) a = fmaf(hrow[j], W_qkv[f * E_ + j], a);
        q[f] = a * qscale;
    }
    if (p == 0) {
#pragma unroll
        for (int f = 0; f < E_; ++f) {
            float a = b_qkv[E_ + f];
#pragma unroll
            for (int j = 0; j < E_; ++j) a = fmaf(hrow[j], W_qkv[(E_ + f) * E_ + j], a);
            ks[t][f] = a;
        }
    } else {
        float v[E_];
#pragma unroll
        for (int f = 0; f < E_; ++f) {
            float a = b_qkv[2 * E_ + f];
#pragma unroll
            for (int j = 0; j < E_; ++j) a = fmaf(hrow[j], W_qkv[(2 * E_ + f) * E_ + j], a);
            v[f] = a;
        }
#pragma unroll
        for (int hh = 0; hh < 4; ++hh)
            us[t][hh] = fmaf(v[2 * hh + 1], wssum[2 * hh + 1], v[2 * hh] * wssum[2 * hh]);
    }
    __syncthreads();

    // s-loop over this thread's half
    float l[4] = {0.f, 0.f, 0.f, 0.f};
    float S4[4] = {0.f, 0.f, 0.f, 0.f};
    const float* kb = &ks[p * 64][0];
    const float* ub = &us[p * 64][0];
#pragma unroll 16
    for (int i = 0; i < 64; ++i) {
        float4 k0 = *(const float4*)(kb + i * 8);
        float4 k1 = *(const float4*)(kb + i * 8 + 4);
        float4 uu = *(const float4*)(ub + i * 4);
        float p0 = exp2f(fmaf(q[1], k0.y, q[0] * k0.x));
        float p1 = exp2f(fmaf(q[3], k0.w, q[2] * k0.z));
        float p2 = exp2f(fmaf(q[5], k1.y, q[4] * k1.x));
        float p3 = exp2f(fmaf(q[7], k1.w, q[6] * k1.z));
        l[0] += p0; l[1] += p1; l[2] += p2; l[3] += p3;
        S4[0] = fmaf(p0, uu.x, S4[0]);
        S4[1] = fmaf(p1, uu.y, S4[1]);
        S4[2] = fmaf(p2, uu.z, S4[2]);
        S4[3] = fmaf(p3, uu.w, S4[3]);
    }

    if (p == 1) {
#pragma unroll
        for (int i = 0; i < 4; ++i) { pacc[t][i] = l[i]; pacc[t][4 + i] = S4[i]; }
    }
    __syncthreads();

    if (p == 0) {
#pragma unroll
        for (int i = 0; i < 4; ++i) { l[i] += pacc[t][i]; S4[i] += pacc[t][4 + i]; }
        float S = bsum_s;
#pragma unroll
        for (int hh = 0; hh < 4; ++hh) S = fmaf(S4[hh], fast_rcp(l[hh]), S);
        tsf_imp[(size_t)b * T_ * C_ + (size_t)t * C_ + c] = fast_sigmoid(S);
        red[t] = S;
    }
    __syncthreads();
    for (int off = 64; off > 0; off >>= 1) {
        if (p == 0 && t < off) red[t] += red[t + off];
        __syncthreads();
    }
    if (tid == 0) feat_imp[bc] = fast_sigmoid(red[0]);
}

// ---------------------------------------------------------------------------
// K3: ts_imp. grid = B*T, block = 64.
// ---------------------------------------------------------------------------
__global__ __launch_bounds__(64) void k_ts(
    const float* __restrict__ x,
    const float* __restrict__ W_ts1, const float* __restrict__ b_ts1,
    const float* __restrict__ W_ts2, const float* __restrict__ b_ts2,
    float* __restrict__ ts_imp)
{
    const int bt = blockIdx.x;
    const int tid = threadIdx.x;
    __shared__ float xs[C_];
    __shared__ float h1[16];
    xs[tid] = x[bt * C_ + tid];
    __syncthreads();
    if (tid < 16) {
        float a = b_ts1[tid];
#pragma unroll
        for (int k = 0; k < C_; ++k) a = fmaf(xs[k], W_ts1[tid * C_ + k], a);
        h1[tid] = 0.5f * a * (1.0f + erff(a * 0.70710678118654752f));
    }
    __syncthreads();
    if (tid == 0) {
        float s = b_ts2[0];
#pragma unroll
        for (int k = 0; k < 16; ++k) s = fmaf(h1[k], W_ts2[k], s);
        ts_imp[bt] = fast_sigmoid(s);
    }
}

// ---------------------------------------------------------------------------
// K4: out0[b,o] = b_out[o] + sum_k fh[b*C..][k] * W_out[o,k]. grid = B.
// ---------------------------------------------------------------------------
__global__ __launch_bounds__(64) void k_out(
    const float* __restrict__ fh, const float* __restrict__ W_out, const float* __restrict__ b_out,
    float* __restrict__ out0)
{
    const int b = blockIdx.x;
    const int tid = threadIdx.x;
    __shared__ float hf[C_ * E_];
    const float4* src = (const float4*)(fh + (b * C_ + tid) * E_);
    float4* dst = (float4*)(hf + tid * E_);
    dst[0] = src[0];
    dst[1] = src[1];
    __syncthreads();
    if (tid < HID_) {
        float a = b_out[tid];
        const float* wo = W_out + tid * (C_ * E_);
        for (int k = 0; k < C_ * E_; ++k) a = fmaf(hf[k], wo[k], a);
        out0[b * HID_ + tid] = a;
    }
}

// ---------------------------------------------------------------------------
extern "C" void kernel_launch(void* const* d_in, const int* in_sizes, int n_in,
                              void* d_out, int out_size, void* d_ws, size_t ws_size,
                              hipStream_t stream) {
    (void)in_sizes; (void)n_in; (void)out_size; (void)ws_size;

    float* out0 = (float*)d_out;                 // (B, HID)    1024
    float* feat = out0 + B_ * HID_;              // (B, C)      2048
    float* tsim = feat + B_ * C_;                // (B, T)      4096
    float* tsf  = tsim + B_ * T_;                // (B, T, C) 262144

    const float* x     = (const float*)d_in[0];
    const float* W_in  = (const float*)d_in[1];
    const float* b_in  = (const float*)d_in[2];
    const float* W_ts1 = (const float*)d_in[3];
    const float* b_ts1 = (const float*)d_in[4];
    const float* W_ts2 = (const float*)d_in[5];
    const float* b_ts2 = (const float*)d_in[6];
    const float* W_ih  = (const float*)d_in[7];
    const float* W_hh  = (const float*)d_in[8];
    const float* b_ih  = (const float*)d_in[9];
    const float* b_hh  = (const float*)d_in[10];
    const float* W_qkv = (const float*)d_in[11];
    const float* b_qkv = (const float*)d_in[12];
    const float* W_o   = (const float*)d_in[13];
    const float* b_o   = (const float*)d_in[14];
    const float* W_out = (const float*)d_in[15];
    const float* b_out = (const float*)d_in[16];

    float* fhb = (float*)d_ws;                   // fh 16K
    float* hsb = fhb + B_ * C_ * E_;             // hs 8M

    hipLaunchKernelGGL(k_gru, dim3(B_ * C_ / 8), dim3(64), 0, stream,
                       x, W_in, b_in, W_ih, W_hh, b_ih, b_hh, hsb, fhb);
    hipLaunchKernelGGL(k_attn, dim3(B_ * C_), dim3(256), 0, stream,
                       hsb, W_qkv, b_qkv, W_o, b_o, feat, tsf);
    hipLaunchKernelGGL(k_ts, dim3(B_ * T_), dim3(64), 0, stream,
                       x, W_ts1, b_ts1, W_ts2, b_ts2, tsim);
    hipLaunchKernelGGL(k_out, dim3(B_), dim3(64), 0, stream,
                       fhb, W_out, b_out, out0);
}

// Round 14
// 93.192 us; speedup vs baseline: 1.1866x; 1.0116x over previous
//
#include <hip/hip_runtime.h>
#include <hip/hip_bf16.h>
#include <math.h>

#define B_ 32
#define T_ 128
#define C_ 64
#define E_ 8
#define HID_ 32

#define LOG2E 1.44269504088896341f

__device__ __forceinline__ float fast_rcp(float x) { return __builtin_amdgcn_rcpf(x); }
__device__ __forceinline__ float fast_sigmoid(float x) {
    return fast_rcp(1.0f + exp2f(-LOG2E * x));
}
__device__ __forceinline__ float fast_tanh(float x) {
    float xc = __builtin_amdgcn_fmed3f(x, -15.0f, 15.0f);
    float t = exp2f(2.0f * LOG2E * xc);
    return (t - 1.0f) * fast_rcp(t + 1.0f);
}

// ---------------------------------------------------------------------------
// K1: GRU with inline xp. 8 chains per 64-thread block. grid = 256.
// Serial-chain trims: tree-reassociated h·W sums (depth 4 vs 8), fmed3 clamp,
// xv prefetch one step ahead.
// ---------------------------------------------------------------------------
__global__ __launch_bounds__(64) void k_gru(
    const float* __restrict__ x, const float* __restrict__ W_in, const float* __restrict__ b_in,
    const float* __restrict__ W_ih, const float* __restrict__ W_hh,
    const float* __restrict__ b_ih, const float* __restrict__ b_hh,
    float* __restrict__ hs, float* __restrict__ fh)
{
    const int tid = threadIdx.x;
    const int ci = tid >> 3;
    const int e = tid & 7;
    const int chain = blockIdx.x * 8 + ci;
    const int b = chain >> 6;
    const int c = chain & 63;

    __shared__ float wsh[8][C_];
    __shared__ float xc[8][T_ + 1];

#pragma unroll
    for (int i = 0; i < 8; ++i) {
        int idx = tid * 8 + i;
        int ci2 = idx >> 6;
        int cc = (blockIdx.x * 8 + ci2) & 63;
        wsh[ci2][idx & 63] = W_in[cc * C_ + (idx & 63)];
    }
    __syncthreads();

    const float bi = b_in[c];
    for (int tt = 0; tt < 16; ++tt) {
        const int t = e * 16 + tt;
        const float4* xr = (const float4*)(x + (b * T_ + t) * C_);
        float a = bi;
#pragma unroll
        for (int k4 = 0; k4 < 16; ++k4) {
            float4 xv = xr[k4];
            a = fmaf(xv.x, wsh[ci][k4 * 4 + 0], a);
            a = fmaf(xv.y, wsh[ci][k4 * 4 + 1], a);
            a = fmaf(xv.z, wsh[ci][k4 * 4 + 2], a);
            a = fmaf(xv.w, wsh[ci][k4 * 4 + 3], a);
        }
        xc[ci][t] = a;
    }
    __syncthreads();

    float wr[E_], wz[E_], wn[E_];
#pragma unroll
    for (int j = 0; j < E_; ++j) {
        wr[j] = W_hh[(c * 24 + 0 * E_ + e) * E_ + j];
        wz[j] = W_hh[(c * 24 + 1 * E_ + e) * E_ + j];
        wn[j] = W_hh[(c * 24 + 2 * E_ + e) * E_ + j];
    }
    const float wir = W_ih[c * 24 + e], wiz = W_ih[c * 24 + E_ + e], win = W_ih[c * 24 + 2 * E_ + e];
    const float cr = b_ih[c * 24 + e] + b_hh[c * 24 + e];                 // bir+bhr
    const float cz = b_ih[c * 24 + E_ + e] + b_hh[c * 24 + E_ + e];      // biz+bhz
    const float bin_ = b_ih[c * 24 + 2 * E_ + e];
    const float bhn  = b_hh[c * 24 + 2 * E_ + e];

    float h = 0.0f;
    float xv = xc[ci][0];
    float* ho = hs + (size_t)chain * T_ * E_ + e;
    for (int t = 0; t < T_; ++t) {
        float xvn = xc[ci][t + 1];                    // pad makes t=127 safe
        float hj0 = __shfl(h, 0, 8), hj1 = __shfl(h, 1, 8);
        float hj2 = __shfl(h, 2, 8), hj3 = __shfl(h, 3, 8);
        float hj4 = __shfl(h, 4, 8), hj5 = __shfl(h, 5, 8);
        float hj6 = __shfl(h, 6, 8), hj7 = __shfl(h, 7, 8);
        float grx = fmaf(xv, wir, cr);
        float gzx = fmaf(xv, wiz, cz);
        float gnx = fmaf(xv, win, bin_);
        // tree-reassociated dot products (depth 4)
        float r0 = fmaf(hj1, wr[1], hj0 * wr[0]);
        float r1 = fmaf(hj3, wr[3], hj2 * wr[2]);
        float r2 = fmaf(hj5, wr[5], hj4 * wr[4]);
        float r3 = fmaf(hj7, wr[7], hj6 * wr[6]);
        float z0 = fmaf(hj1, wz[1], hj0 * wz[0]);
        float z1 = fmaf(hj3, wz[3], hj2 * wz[2]);
        float z2 = fmaf(hj5, wz[5], hj4 * wz[4]);
        float z3 = fmaf(hj7, wz[7], hj6 * wz[6]);
        float n0 = fmaf(hj1, wn[1], hj0 * wn[0]);
        float n1 = fmaf(hj3, wn[3], hj2 * wn[2]);
        float n2 = fmaf(hj5, wn[5], hj4 * wn[4]);
        float n3 = fmaf(hj7, wn[7], hj6 * wn[6]);
        float gr = grx + ((r0 + r1) + (r2 + r3));
        float gz = gzx + ((z0 + z1) + (z2 + z3));
        float hn = bhn + ((n0 + n1) + (n2 + n3));
        float r = fast_sigmoid(gr);
        float z = fast_sigmoid(gz);
        float nn = fast_tanh(fmaf(r, hn, gnx));
        h = fmaf(z, h - nn, nn);
        ho[t * E_] = h;
        xv = xvn;
    }
    fh[chain * E_ + e] = h;
}

// ---------------------------------------------------------------------------
// K2: attention, 2-row register tiling + s-quarter split. grid = B*C,
// block = 256: t2 = tid&63 (rows t2, t2+64), sq = tid>>6 (s in [32sq,32sq+32)).
// Within a wave all lanes share sq -> k/u LDS reads are broadcasts.
// q shared via transposed qsT (conflict-free); staging rows live in registers.
// ---------------------------------------------------------------------------
__global__ __launch_bounds__(256) void k_attn(
    const float* __restrict__ hs, const float* __restrict__ W_qkv, const float* __restrict__ b_qkv,
    const float* __restrict__ W_o, const float* __restrict__ b_o,
    float* __restrict__ feat_imp, float* __restrict__ tsf_imp)
{
    const int bc = blockIdx.x;
    const int b = bc >> 6, c = bc & 63;
    const int tid = threadIdx.x;
    const int t2 = tid & 63;
    const int sq = tid >> 6;

    __shared__ __align__(16) float ks[T_][E_];
    __shared__ __align__(16) float us[T_][4];
    __shared__ float qsT[E_][T_];
    __shared__ float pacc[3][T_][8];
    __shared__ float red[T_];

    const float qscale = 0.70710678118654752f * LOG2E;

    // --- staging: tid<128 -> q+k of row tid; tid>=128 -> u of row tid-128
    {
        const int row = (tid < 128) ? tid : (tid - 128);
        const float4* hp = (const float4*)(hs + (size_t)bc * T_ * E_ + row * E_);
        float4 h0 = hp[0], h1 = hp[1];
        float hr[E_] = {h0.x, h0.y, h0.z, h0.w, h1.x, h1.y, h1.z, h1.w};
        if (tid < 128) {
            float kv[E_];
#pragma unroll
            for (int f = 0; f < E_; ++f) {
                float a = b_qkv[E_ + f];
#pragma unroll
                for (int j = 0; j < E_; ++j) a = fmaf(hr[j], W_qkv[(E_ + f) * E_ + j], a);
                kv[f] = a;
            }
            ((float4*)&ks[row][0])[0] = make_float4(kv[0], kv[1], kv[2], kv[3]);
            ((float4*)&ks[row][0])[1] = make_float4(kv[4], kv[5], kv[6], kv[7]);
#pragma unroll
            for (int f = 0; f < E_; ++f) {
                float a = b_qkv[f];
#pragma unroll
                for (int j = 0; j < E_; ++j) a = fmaf(hr[j], W_qkv[f * E_ + j], a);
                qsT[f][row] = a * qscale;                 // transposed: lanes->banks
            }
        } else {
            float ws[E_];
#pragma unroll
            for (int d = 0; d < E_; ++d) {                // uniform -> scalar loads
                float w = 0.0f;
#pragma unroll
                for (int fp = 0; fp < E_; ++fp) w += W_o[fp * E_ + d];
                ws[d] = w;
            }
            float vv[E_];
#pragma unroll
            for (int f = 0; f < E_; ++f) {
                float a = b_qkv[2 * E_ + f];
#pragma unroll
                for (int j = 0; j < E_; ++j) a = fmaf(hr[j], W_qkv[(2 * E_ + f) * E_ + j], a);
                vv[f] = a;
            }
            float4 uu;
            uu.x = fmaf(vv[1], ws[1], vv[0] * ws[0]);
            uu.y = fmaf(vv[3], ws[3], vv[2] * ws[2]);
            uu.z = fmaf(vv[5], ws[5], vv[4] * ws[4]);
            uu.w = fmaf(vv[7], ws[7], vv[6] * ws[6]);
            *((float4*)&us[row][0]) = uu;
        }
    }
    __syncthreads();

    // q for this thread's two rows (conflict-free reads from qsT)
    float q0[E_], q1[E_];
#pragma unroll
    for (int f = 0; f < E_; ++f) { q0[f] = qsT[f][t2]; q1[f] = qsT[f][t2 + 64]; }

    // --- main loop: 32 s-values, k/u broadcast-read, 2 rows share each read
    float l0[4] = {0.f,0.f,0.f,0.f}, S0[4] = {0.f,0.f,0.f,0.f};
    float l1[4] = {0.f,0.f,0.f,0.f}, S1[4] = {0.f,0.f,0.f,0.f};
    const float* kb = &ks[sq * 32][0];
    const float* ub = &us[sq * 32][0];
#pragma unroll 8
    for (int i = 0; i < 32; ++i) {
        float4 k0 = *(const float4*)(kb + i * 8);
        float4 k1 = *(const float4*)(kb + i * 8 + 4);
        float4 uu = *(const float4*)(ub + i * 4);
        float p00 = exp2f(fmaf(q0[1], k0.y, q0[0] * k0.x));
        float p01 = exp2f(fmaf(q0[3], k0.w, q0[2] * k0.z));
        float p02 = exp2f(fmaf(q0[5], k1.y, q0[4] * k1.x));
        float p03 = exp2f(fmaf(q0[7], k1.w, q0[6] * k1.z));
        float p10 = exp2f(fmaf(q1[1], k0.y, q1[0] * k0.x));
        float p11 = exp2f(fmaf(q1[3], k0.w, q1[2] * k0.z));
        float p12 = exp2f(fmaf(q1[5], k1.y, q1[4] * k1.x));
        float p13 = exp2f(fmaf(q1[7], k1.w, q1[6] * k1.z));
        l0[0] += p00; l0[1] += p01; l0[2] += p02; l0[3] += p03;
        l1[0] += p10; l1[1] += p11; l1[2] += p12; l1[3] += p13;
        S0[0] = fmaf(p00, uu.x, S0[0]); S0[1] = fmaf(p01, uu.y, S0[1]);
        S0[2] = fmaf(p02, uu.z, S0[2]); S0[3] = fmaf(p03, uu.w, S0[3]);
        S1[0] = fmaf(p10, uu.x, S1[0]); S1[1] = fmaf(p11, uu.y, S1[1]);
        S1[2] = fmaf(p12, uu.z, S1[2]); S1[3] = fmaf(p13, uu.w, S1[3]);
    }

    // --- combine partial quarters
    if (sq > 0) {
        float* pr = &pacc[sq - 1][t2][0];
#pragma unroll
        for (int i = 0; i < 4; ++i) { pr[i] = l0[i]; pr[4 + i] = S0[i]; }
        pr = &pacc[sq - 1][t2 + 64][0];
#pragma unroll
        for (int i = 0; i < 4; ++i) { pr[i] = l1[i]; pr[4 + i] = S1[i]; }
    }
    __syncthreads();

    if (sq == 0) {
        float bsum = 0.0f;
#pragma unroll
        for (int fp = 0; fp < E_; ++fp) bsum += b_o[fp];    // uniform scalar loads
#pragma unroll
        for (int qq = 0; qq < 3; ++qq) {
#pragma unroll
            for (int i = 0; i < 4; ++i) {
                l0[i] += pacc[qq][t2][i];       S0[i] += pacc[qq][t2][4 + i];
                l1[i] += pacc[qq][t2 + 64][i];  S1[i] += pacc[qq][t2 + 64][4 + i];
            }
        }
        float Sa = bsum, Sb = bsum;
#pragma unroll
        for (int hh = 0; hh < 4; ++hh) {
            Sa = fmaf(S0[hh], fast_rcp(l0[hh]), Sa);
            Sb = fmaf(S1[hh], fast_rcp(l1[hh]), Sb);
        }
        tsf_imp[(size_t)b * T_ * C_ + (size_t)t2 * C_ + c] = fast_sigmoid(Sa);
        tsf_imp[(size_t)b * T_ * C_ + (size_t)(t2 + 64) * C_ + c] = fast_sigmoid(Sb);
        red[t2] = Sa;
        red[t2 + 64] = Sb;
    }
    __syncthreads();
    for (int off = 64; off > 0; off >>= 1) {
        if (tid < off) red[tid] += red[tid + off];
        __syncthreads();
    }
    if (tid == 0) feat_imp[bc] = fast_sigmoid(red[0]);
}

// ---------------------------------------------------------------------------
// K3: ts_imp. grid = B*T, block = 64.
// ---------------------------------------------------------------------------
__global__ __launch_bounds__(64) void k_ts(
    const float* __restrict__ x,
    const float* __restrict__ W_ts1, const float* __restrict__ b_ts1,
    const float* __restrict__ W_ts2, const float* __restrict__ b_ts2,
    float* __restrict__ ts_imp)
{
    const int bt = blockIdx.x;
    const int tid = threadIdx.x;
    __shared__ float xs[C_];
    __shared__ float h1[16];
    xs[tid] = x[bt * C_ + tid];
    __syncthreads();
    if (tid < 16) {
        float a = b_ts1[tid];
#pragma unroll
        for (int k = 0; k < C_; ++k) a = fmaf(xs[k], W_ts1[tid * C_ + k], a);
        h1[tid] = 0.5f * a * (1.0f + erff(a * 0.70710678118654752f));
    }
    __syncthreads();
    if (tid == 0) {
        float s = b_ts2[0];
#pragma unroll
        for (int k = 0; k < 16; ++k) s = fmaf(h1[k], W_ts2[k], s);
        ts_imp[bt] = fast_sigmoid(s);
    }
}

// ---------------------------------------------------------------------------
// K4: out0[b,o] = b_out[o] + sum_k fh[b*C..][k] * W_out[o,k]. grid = B.
// ---------------------------------------------------------------------------
__global__ __launch_bounds__(64) void k_out(
    const float* __restrict__ fh, const float* __restrict__ W_out, const float* __restrict__ b_out,
    float* __restrict__ out0)
{
    const int b = blockIdx.x;
    const int tid = threadIdx.x;
    __shared__ float hf[C_ * E_];
    const float4* src = (const float4*)(fh + (b * C_ + tid) * E_);
    float4* dst = (float4*)(hf + tid * E_);
    dst[0] = src[0];
    dst[1] = src[1];
    __syncthreads();
    if (tid < HID_) {
        float a = b_out[tid];
        const float* wo = W_out + tid * (C_ * E_);
        for (int k = 0; k < C_ * E_; ++k) a = fmaf(hf[k], wo[k], a);
        out0[b * HID_ + tid] = a;
    }
}

// ---------------------------------------------------------------------------
extern "C" void kernel_launch(void* const* d_in, const int* in_sizes, int n_in,
                              void* d_out, int out_size, void* d_ws, size_t ws_size,
                              hipStream_t stream) {
    (void)in_sizes; (void)n_in; (void)out_size; (void)ws_size;

    float* out0 = (float*)d_out;                 // (B, HID)    1024
    float* feat = out0 + B_ * HID_;              // (B, C)      2048
    float* tsim = feat + B_ * C_;                // (B, T)      4096
    float* tsf  = tsim + B_ * T_;                // (B, T, C) 262144

    const float* x     = (const float*)d_in[0];
    const float* W_in  = (const float*)d_in[1];
    const float* b_in  = (const float*)d_in[2];
    const float* W_ts1 = (const float*)d_in[3];
    const float* b_ts1 = (const float*)d_in[4];
    const float* W_ts2 = (const float*)d_in[5];
    const float* b_ts2 = (const float*)d_in[6];
    const float* W_ih  = (const float*)d_in[7];
    const float* W_hh  = (const float*)d_in[8];
    const float* b_ih  = (const float*)d_in[9];
    const float* b_hh  = (const float*)d_in[10];
    const float* W_qkv = (const float*)d_in[11];
    const float* b_qkv = (const float*)d_in[12];
    const float* W_o   = (const float*)d_in[13];
    const float* b_o   = (const float*)d_in[14];
    const float* W_out = (const float*)d_in[15];
    const float* b_out = (const float*)d_in[16];

    float* fhb = (float*)d_ws;                   // fh 16K
    float* hsb = fhb + B_ * C_ * E_;             // hs 8M

    hipLaunchKernelGGL(k_gru, dim3(B_ * C_ / 8), dim3(64), 0, stream,
                       x, W_in, b_in, W_ih, W_hh, b_ih, b_hh, hsb, fhb);
    hipLaunchKernelGGL(k_attn, dim3(B_ * C_), dim3(256), 0, stream,
                       hsb, W_qkv, b_qkv, W_o, b_o, feat, tsf);
    hipLaunchKernelGGL(k_ts, dim3(B_ * T_), dim3(64), 0, stream,
                       x, W_ts1, b_ts1, W_ts2, b_ts2, tsim);
    hipLaunchKernelGGL(k_out, dim3(B_), dim3(64), 0, stream,
                       fhb, W_out, b_out, out0);
}